// Round 16
// baseline (451.753 us; speedup 1.0000x reference)
//
#include <hip/hip_runtime.h>
#include <hip/hip_bf16.h>

#define BATCH 65536
#define DK 512
#define DV 512
#define DH 64
#define BMR 32          // rows per block: 2 m-tiles of 16

typedef __attribute__((ext_vector_type(8))) short bf16x8;
typedef __attribute__((ext_vector_type(4))) float f32x4;

// raw barrier: drain LDS ops only (not vmcnt)
#define LGKM_BAR() do { asm volatile("s_waitcnt lgkmcnt(0)" ::: "memory"); \
                        __builtin_amdgcn_s_barrier(); } while (0)

// FRAGMENT-ORDERED bf16 weight images (one coalesced 1KB load per wave-frag):
//   shorts [0, 32768):       W1F  (4 tiles x 16 kk x 64 lanes x 8)
//   shorts [32768, 65536):   W2F  (32 tiles x 2 kh x 64 lanes x 8)
//   shorts [65536, 327680):  WpF  (32 tiles x 16 kk x 64 lanes x 8)
__device__ __align__(16) short g_wb[327680];

__device__ __forceinline__ short f2bf(float f) {
    union { __hip_bfloat16 h; short s; } u;
    u.h = __float2bfloat16(f);
    return u.s;
}

__device__ __forceinline__ bf16x8 pack8(float4 a, float4 b) {
    bf16x8 r;
    r[0] = f2bf(a.x); r[1] = f2bf(a.y); r[2] = f2bf(a.z); r[3] = f2bf(a.w);
    r[4] = f2bf(b.x); r[5] = f2bf(b.y); r[6] = f2bf(b.z); r[7] = f2bf(b.w);
    return r;
}

__global__ __launch_bounds__(256) void conv_weights(
    const float* __restrict__ W1, const float* __restrict__ W2,
    const float* __restrict__ Wp)
{
    int f = blockIdx.x * 256 + threadIdx.x;
    int lane = f & 63;
    const float* src; int stride, row, col;
    if (f < 4096) {                    // W1F
        int t = f >> 10, kk = (f >> 6) & 15;
        src = W1; stride = DK;
        row = t * 16 + (lane & 15); col = kk * 32 + (lane >> 4) * 8;
    } else if (f < 8192) {             // W2F
        int g = f - 4096; int t = g >> 7, kh = (g >> 6) & 1;
        src = W2; stride = DH;
        row = t * 16 + (lane & 15); col = kh * 32 + (lane >> 4) * 8;
    } else {                           // WpF
        int g = f - 8192; int t = g >> 10, kk = (g >> 6) & 15;
        src = Wp; stride = DK;
        row = t * 16 + (lane & 15); col = kk * 32 + (lane >> 4) * 8;
    }
    const float* p = src + (long)row * stride + col;
    float4 a = *reinterpret_cast<const float4*>(p);
    float4 b = *reinterpret_cast<const float4*>(p + 4);
    *reinterpret_cast<bf16x8*>(g_wb + (long)f * 8) = pack8(a, b);
}

// LDS (36864 B -> 4 blocks/CU):
//   [0, 32768):      key tile bf16 [32 rows][512], byte ^= (row&7)<<4
//   [32768, 36864):  h park: 2 slots x 2KB (rows 0-15, 16-31); later F partials
#define KOF 0
#define HOF 32768

__global__ __launch_bounds__(256, 4) void fused_free_energy(
    const float* __restrict__ key, const float* __restrict__ value,
    const float* __restrict__ b1, const float* __restrict__ b2,
    const float* __restrict__ pb,
    float* __restrict__ outF, float* __restrict__ outPred,
    float* __restrict__ outPrec, float* __restrict__ outErr)
{
    __shared__ __align__(16) char lds[36864];

    const bf16x8* W1F = reinterpret_cast<const bf16x8*>(g_wb);
    const bf16x8* W2F = reinterpret_cast<const bf16x8*>(g_wb + 32768);
    const bf16x8* WpF = reinterpret_cast<const bf16x8*>(g_wb + 65536);

    const int tid  = threadIdx.x;
    const int wave = tid >> 6;
    const int lane = tid & 63;
    const int lh   = lane & 15;
    const int lg   = lane >> 4;
    const long row0 = (long)blockIdx.x * BMR;
    const f32x4 zf = {0.f, 0.f, 0.f, 0.f};

    // ---- stage key tile (32 x 512) f32 -> bf16, swizzled ----
    #pragma unroll
    for (int i = 0; i < 8; ++i) {                // 2048 8-elem chunks / 256 thr
        int idx = i * 256 + tid;
        int r = idx >> 6, c8 = idx & 63;
        const float* p = key + (row0 + r) * DK + c8 * 8;
        float4 a = *reinterpret_cast<const float4*>(p);
        float4 b = *reinterpret_cast<const float4*>(p + 4);
        int byte = (r * 1024 + c8 * 16) ^ ((r & 7) << 4);
        *reinterpret_cast<bf16x8*>(lds + KOF + byte) = pack8(a, b);
    }
    LGKM_BAR();

    // key B-fragment: m-tile mt, k-chunk kk; row = mt*16+lh ((row&7)==(lh&7))
    #define KFRAG(mt, kk) (*reinterpret_cast<const bf16x8*>( \
        lds + KOF + (((mt) * 16384 + lh * 1024 + (kk) * 64 + lg * 16) ^ ((lh & 7) << 4))))

    // ---- GEMM1: wave w (w<2) computes h for m-tile w: h = gelu(key@W1^T + b1) ----
    if (wave < 2) {
        #pragma unroll
        for (int jt = 0; jt < 4; ++jt) {
            f32x4 aE = zf, aO = zf;
            #pragma unroll
            for (int kk = 0; kk < 16; kk += 2) {
                bf16x8 f0 = W1F[(jt * 16 + kk) * 64 + lane];
                bf16x8 f1 = W1F[(jt * 16 + kk + 1) * 64 + lane];
                aE = __builtin_amdgcn_mfma_f32_16x16x32_bf16(f0, KFRAG(wave, kk),     aE, 0, 0, 0);
                aO = __builtin_amdgcn_mfma_f32_16x16x32_bf16(f1, KFRAG(wave, kk + 1), aO, 0, 0, 0);
            }
            float4 b1v = *reinterpret_cast<const float4*>(b1 + jt * 16 + lg * 4);
            float b1a[4] = {b1v.x, b1v.y, b1v.z, b1v.w};
            short hs[4];
            #pragma unroll
            for (int r = 0; r < 4; ++r) {
                float z = aE[r] + aO[r] + b1a[r];
                float g = 0.5f * z * (1.0f + erff(z * 0.70710678f));  // exact GELU
                hs[r] = f2bf(g);
            }
            int hb = HOF + wave * 2048 + ((lh * 128 + jt * 32 + lg * 8) ^ ((lh & 7) << 4));
            short4 hv = {hs[0], hs[1], hs[2], hs[3]};
            *reinterpret_cast<short4*>(lds + hb) = hv;
        }
    }
    LGKM_BAR();

    // h B-fragments for both m-tiles
    bf16x8 hreg[2][2];
    #pragma unroll
    for (int mt = 0; mt < 2; ++mt)
        #pragma unroll
        for (int kh = 0; kh < 2; ++kh) {
            int byte = (lh * 128 + kh * 64 + lg * 16) ^ ((lh & 7) << 4);
            hreg[mt][kh] = *reinterpret_cast<const bf16x8*>(lds + HOF + mt * 2048 + byte);
        }
    LGKM_BAR();   // all waves have hreg; hpark reusable for F partials

    // ---- main loop: wave owns col-tiles [wave*8, wave*8+8); 2 m-tiles each ----
    float facc0 = 0.f, facc1 = 0.f;
    const long grow0 = row0 + lh;
    const long grow1 = grow0 + 16;
    const float* vrow0 = value + grow0 * (long)DV;
    const float* vrow1 = value + grow1 * (long)DV;

    {
        int nb0 = (wave * 8) * 16 + lg * 4;
        float4 vcur0 = *reinterpret_cast<const float4*>(vrow0 + nb0);
        float4 vcur1 = *reinterpret_cast<const float4*>(vrow1 + nb0);

        #pragma unroll 2
        for (int it = 0; it < 8; ++it) {
            const int tt = wave * 8 + it;
            const int nb = tt * 16 + lg * 4;

            // prefetch next tile's value
            const int nbn = (it < 7) ? nb + 16 : nb;
            float4 vnx0 = *reinterpret_cast<const float4*>(vrow0 + nbn);
            float4 vnx1 = *reinterpret_cast<const float4*>(vrow1 + nbn);

            // GEMM3: each Wp fragment feeds BOTH m-tiles (2 MFMAs per load)
            f32x4 a0 = zf, a1 = zf;
            #pragma unroll
            for (int kk = 0; kk < 16; ++kk) {
                bf16x8 f0 = WpF[(tt * 16 + kk) * 64 + lane];
                a0 = __builtin_amdgcn_mfma_f32_16x16x32_bf16(f0, KFRAG(0, kk), a0, 0, 0, 0);
                a1 = __builtin_amdgcn_mfma_f32_16x16x32_bf16(f0, KFRAG(1, kk), a1, 0, 0, 0);
            }
            // GEMM2
            f32x4 c0 = zf, c1 = zf;
            #pragma unroll
            for (int kh = 0; kh < 2; ++kh) {
                bf16x8 f = W2F[(tt * 2 + kh) * 64 + lane];
                c0 = __builtin_amdgcn_mfma_f32_16x16x32_bf16(f, hreg[0][kh], c0, 0, 0, 0);
                c1 = __builtin_amdgcn_mfma_f32_16x16x32_bf16(f, hreg[1][kh], c1, 0, 0, 0);
            }

            float4 b2v = *reinterpret_cast<const float4*>(b2 + nb);
            float4 pbv = *reinterpret_cast<const float4*>(pb + nb);
            float b2a[4] = {b2v.x, b2v.y, b2v.z, b2v.w};
            float pba[4] = {pbv.x, pbv.y, pbv.z, pbv.w};

            // epilogue m-tile 0 (row grow0)
            {
                float va[4] = {vcur0.x, vcur0.y, vcur0.z, vcur0.w};
                float prv[4], pcv[4], erv[4];
                #pragma unroll
                for (int r = 0; r < 4; ++r) {
                    float z    = a0[r] + pba[r];
                    float pred = c0[r] + b2a[r];
                    float prec = fmaxf(z, 0.f) + __logf(1.0f + __expf(-fabsf(z))) + 0.01f;
                    float err  = fminf(fmaxf(va[r] - pred, -3.f), 3.f);
                    prv[r] = pred; pcv[r] = prec; erv[r] = err;
                    facc0 += prec * err * err - __logf(prec);
                }
                float4 pr4 = {prv[0], prv[1], prv[2], prv[3]};
                float4 pc4 = {pcv[0], pcv[1], pcv[2], pcv[3]};
                float4 er4 = {erv[0], erv[1], erv[2], erv[3]};
                long ga = grow0 * (long)DV + nb;
                *reinterpret_cast<float4*>(outPred + ga) = pr4;
                *reinterpret_cast<float4*>(outPrec + ga) = pc4;
                *reinterpret_cast<float4*>(outErr  + ga) = er4;
            }
            // epilogue m-tile 1 (row grow1)
            {
                float va[4] = {vcur1.x, vcur1.y, vcur1.z, vcur1.w};
                float prv[4], pcv[4], erv[4];
                #pragma unroll
                for (int r = 0; r < 4; ++r) {
                    float z    = a1[r] + pba[r];
                    float pred = c1[r] + b2a[r];
                    float prec = fmaxf(z, 0.f) + __logf(1.0f + __expf(-fabsf(z))) + 0.01f;
                    float err  = fminf(fmaxf(va[r] - pred, -3.f), 3.f);
                    prv[r] = pred; pcv[r] = prec; erv[r] = err;
                    facc1 += prec * err * err - __logf(prec);
                }
                float4 pr4 = {prv[0], prv[1], prv[2], prv[3]};
                float4 pc4 = {pcv[0], pcv[1], pcv[2], pcv[3]};
                float4 er4 = {erv[0], erv[1], erv[2], erv[3]};
                long ga = grow1 * (long)DV + nb;
                *reinterpret_cast<float4*>(outPred + ga) = pr4;
                *reinterpret_cast<float4*>(outPrec + ga) = pc4;
                *reinterpret_cast<float4*>(outErr  + ga) = er4;
            }

            vcur0 = vnx0; vcur1 = vnx1;
        }
    }

    // ---- F: reduce over lg groups, then across waves via LDS ----
    facc0 += __shfl_xor(facc0, 16, 64);
    facc0 += __shfl_xor(facc0, 32, 64);
    facc1 += __shfl_xor(facc1, 16, 64);
    facc1 += __shfl_xor(facc1, 32, 64);
    float* fpart = reinterpret_cast<float*>(lds + HOF);   // [4 waves][32 rows]
    if (lane < 16) {
        fpart[wave * 32 + lh]      = facc0;
        fpart[wave * 32 + 16 + lh] = facc1;
    }
    __syncthreads();
    if (tid < 32) {
        float s = fpart[tid] + fpart[32 + tid] + fpart[64 + tid] + fpart[96 + tid];
        outF[row0 + tid] = s * (1.0f / 512.0f);
    }
}

extern "C" void kernel_launch(void* const* d_in, const int* in_sizes, int n_in,
                              void* d_out, int out_size, void* d_ws, size_t ws_size,
                              hipStream_t stream) {
    const float* key   = (const float*)d_in[0];
    const float* value = (const float*)d_in[1];
    const float* W1    = (const float*)d_in[2];
    const float* b1    = (const float*)d_in[3];
    const float* W2    = (const float*)d_in[4];
    const float* b2    = (const float*)d_in[5];
    const float* Wp    = (const float*)d_in[6];
    const float* pb    = (const float*)d_in[7];

    float* outF    = (float*)d_out;
    float* outPred = outF + BATCH;
    float* outPrec = outPred + (long)BATCH * DV;
    float* outErr  = outPrec + (long)BATCH * DV;

    conv_weights<<<160, 256, 0, stream>>>(W1, W2, Wp);
    fused_free_energy<<<BATCH / BMR, 256, 0, stream>>>(key, value, b1, b2, pb,
                                                       outF, outPred, outPrec, outErr);
}

// Round 17
// 249.457 us; speedup vs baseline: 1.8109x; 1.8109x over previous
//
#include <hip/hip_runtime.h>
#include <hip/hip_bf16.h>

#define BATCH 65536
#define DK 512
#define DV 512
#define DH 64
#define BMR 32          // rows per block: 2 m-tiles of 16

typedef __attribute__((ext_vector_type(8))) short bf16x8;
typedef __attribute__((ext_vector_type(4))) float f32x4;

// raw barrier: drain LDS ops only (vmcnt stays in flight)
#define LGKM_BAR() do { asm volatile("s_waitcnt lgkmcnt(0)" ::: "memory"); \
                        __builtin_amdgcn_s_barrier(); } while (0)

// FRAGMENT-ORDERED bf16 weight images (one coalesced 1KB load per wave-frag):
//   shorts [0, 32768):       W1F  (4 tiles x 16 kk x 64 lanes x 8)
//   shorts [32768, 65536):   W2F  (32 tiles x 2 kh x 64 lanes x 8)
//   shorts [65536, 327680):  WpF  (32 tiles x 16 kk x 64 lanes x 8)
__device__ __align__(16) short g_wb[327680];

__device__ __forceinline__ short f2bf(float f) {
    union { __hip_bfloat16 h; short s; } u;
    u.h = __float2bfloat16(f);
    return u.s;
}

__device__ __forceinline__ bf16x8 pack8(float4 a, float4 b) {
    bf16x8 r;
    r[0] = f2bf(a.x); r[1] = f2bf(a.y); r[2] = f2bf(a.z); r[3] = f2bf(a.w);
    r[4] = f2bf(b.x); r[5] = f2bf(b.y); r[6] = f2bf(b.z); r[7] = f2bf(b.w);
    return r;
}

__global__ __launch_bounds__(256) void conv_weights(
    const float* __restrict__ W1, const float* __restrict__ W2,
    const float* __restrict__ Wp)
{
    int f = blockIdx.x * 256 + threadIdx.x;
    int lane = f & 63;
    const float* src; int stride, row, col;
    if (f < 4096) {                    // W1F
        int t = f >> 10, kk = (f >> 6) & 15;
        src = W1; stride = DK;
        row = t * 16 + (lane & 15); col = kk * 32 + (lane >> 4) * 8;
    } else if (f < 8192) {             // W2F
        int g = f - 4096; int t = g >> 7, kh = (g >> 6) & 1;
        src = W2; stride = DH;
        row = t * 16 + (lane & 15); col = kh * 32 + (lane >> 4) * 8;
    } else {                           // WpF
        int g = f - 8192; int t = g >> 10, kk = (g >> 6) & 15;
        src = Wp; stride = DK;
        row = t * 16 + (lane & 15); col = kk * 32 + (lane >> 4) * 8;
    }
    const float* p = src + (long)row * stride + col;
    float4 a = *reinterpret_cast<const float4*>(p);
    float4 b = *reinterpret_cast<const float4*>(p + 4);
    *reinterpret_cast<bf16x8*>(g_wb + (long)f * 8) = pack8(a, b);
}

// LDS (49152 B -> 3 blocks/CU):
//   [0, 32768):      key tile bf16 [32 rows][512], byte ^= (row&7)<<4
//   [32768, 40960):  XP: pred stage f32 [32 rows][64 cols] (h-park pre-loop)
//   [40960, 49152):  XZ: z3 stage  f32 [32 rows][64 cols]
#define KOF 0
#define XP  32768
#define XZ  40960

__global__ __launch_bounds__(256, 3) void fused_free_energy(
    const float* __restrict__ key, const float* __restrict__ value,
    const float* __restrict__ b1, const float* __restrict__ b2,
    const float* __restrict__ pb,
    float* __restrict__ outF, float* __restrict__ outPred,
    float* __restrict__ outPrec, float* __restrict__ outErr)
{
    __shared__ __align__(16) char lds[49152];

    const bf16x8* W1F = reinterpret_cast<const bf16x8*>(g_wb);
    const bf16x8* W2F = reinterpret_cast<const bf16x8*>(g_wb + 32768);
    const bf16x8* WpF = reinterpret_cast<const bf16x8*>(g_wb + 65536);

    const int tid  = threadIdx.x;
    const int wave = tid >> 6;
    const int lane = tid & 63;
    const int lh   = lane & 15;
    const int lg   = lane >> 4;
    const long row0 = (long)blockIdx.x * BMR;
    const f32x4 zf = {0.f, 0.f, 0.f, 0.f};

    // writeback geometry (thread-constant): thread owns rows rw, rw+16, col chunk cw
    const int rw = tid >> 4;                     // 0..15
    const int cw = (tid & 15) * 4;               // f32 col within 64-col phase
    const float* vrow0 = value + (row0 + rw) * (long)DV + cw;
    const float* vrow1 = vrow0 + 16 * (long)DV;

    // ---- stage key tile (32 x 512) f32 -> bf16, swizzled ----
    #pragma unroll
    for (int i = 0; i < 8; ++i) {                // 2048 8-elem chunks / 256 thr
        int idx = i * 256 + tid;
        int r = idx >> 6, c8 = idx & 63;
        const float* p = key + (row0 + r) * DK + c8 * 8;
        float4 a = *reinterpret_cast<const float4*>(p);
        float4 b = *reinterpret_cast<const float4*>(p + 4);
        int byte = (r * 1024 + c8 * 16) ^ ((r & 7) << 4);
        *reinterpret_cast<bf16x8*>(lds + KOF + byte) = pack8(a, b);
    }
    LGKM_BAR();

    // key B-fragment: m-tile mt, k-chunk kk; (row&7)==(lh&7)
    #define KFRAG(mt, kk) (*reinterpret_cast<const bf16x8*>( \
        lds + KOF + (((mt) * 16384 + lh * 1024 + (kk) * 64 + lg * 16) ^ ((lh & 7) << 4))))

    // ---- GEMM1: wave w (w<2) computes h for m-tile w ----
    if (wave < 2) {
        #pragma unroll
        for (int jt = 0; jt < 4; ++jt) {
            f32x4 aE = zf, aO = zf;
            #pragma unroll
            for (int kk = 0; kk < 16; kk += 2) {
                bf16x8 f0 = W1F[(jt * 16 + kk) * 64 + lane];
                bf16x8 f1 = W1F[(jt * 16 + kk + 1) * 64 + lane];
                aE = __builtin_amdgcn_mfma_f32_16x16x32_bf16(f0, KFRAG(wave, kk),     aE, 0, 0, 0);
                aO = __builtin_amdgcn_mfma_f32_16x16x32_bf16(f1, KFRAG(wave, kk + 1), aO, 0, 0, 0);
            }
            float4 b1v = *reinterpret_cast<const float4*>(b1 + jt * 16 + lg * 4);
            float b1a[4] = {b1v.x, b1v.y, b1v.z, b1v.w};
            short hs[4];
            #pragma unroll
            for (int r = 0; r < 4; ++r) {
                float z = aE[r] + aO[r] + b1a[r];
                float g = 0.5f * z * (1.0f + erff(z * 0.70710678f));  // exact GELU
                hs[r] = f2bf(g);
            }
            int hb = XP + wave * 2048 + ((lh * 128 + jt * 32 + lg * 8) ^ ((lh & 7) << 4));
            short4 hv = {hs[0], hs[1], hs[2], hs[3]};
            *reinterpret_cast<short4*>(lds + hb) = hv;
        }
    }
    LGKM_BAR();
    bf16x8 hreg[2][2];
    #pragma unroll
    for (int mt = 0; mt < 2; ++mt)
        #pragma unroll
        for (int kh = 0; kh < 2; ++kh) {
            int byte = (lh * 128 + kh * 64 + lg * 16) ^ ((lh & 7) << 4);
            hreg[mt][kh] = *reinterpret_cast<const bf16x8*>(lds + XP + mt * 2048 + byte);
        }
    LGKM_BAR();   // h consumed; XP free for staging

    // ---- main loop: 8 phases x 64 cols; phase tile tt = ph*4 + wave ----
    float facc0 = 0.f, facc1 = 0.f;

    #pragma unroll 1
    for (int ph = 0; ph < 8; ++ph) {
        // this phase's value loads (consumed after the barrier; vmcnt not drained there)
        float4 va0 = *reinterpret_cast<const float4*>(vrow0 + ph * 64);
        float4 va1 = *reinterpret_cast<const float4*>(vrow1 + ph * 64);

        // COMPUTE: one col-tile, both m-tiles; each Wp fragment feeds 2 MFMAs
        const int tt = ph * 4 + wave;
        f32x4 a0 = zf, a1 = zf;
        #pragma unroll
        for (int kk = 0; kk < 16; ++kk) {
            bf16x8 f0 = WpF[(tt * 16 + kk) * 64 + lane];
            a0 = __builtin_amdgcn_mfma_f32_16x16x32_bf16(f0, KFRAG(0, kk), a0, 0, 0, 0);
            a1 = __builtin_amdgcn_mfma_f32_16x16x32_bf16(f0, KFRAG(1, kk), a1, 0, 0, 0);
        }
        f32x4 c0 = zf, c1 = zf;
        #pragma unroll
        for (int kh = 0; kh < 2; ++kh) {
            bf16x8 f = W2F[(tt * 2 + kh) * 64 + lane];
            c0 = __builtin_amdgcn_mfma_f32_16x16x32_bf16(f, hreg[0][kh], c0, 0, 0, 0);
            c1 = __builtin_amdgcn_mfma_f32_16x16x32_bf16(f, hreg[1][kh], c1, 0, 0, 0);
        }

        int nb = tt * 16 + lg * 4;
        float4 b2v = *reinterpret_cast<const float4*>(b2 + nb);
        float4 pbv = *reinterpret_cast<const float4*>(pb + nb);

        // stage pz/zz for both m-tiles: XP/XZ [32 rows][64 cols] f32, swizzled
        {
            f32x4 pz, zz;
            pz[0] = c0[0] + b2v.x; pz[1] = c0[1] + b2v.y;
            pz[2] = c0[2] + b2v.z; pz[3] = c0[3] + b2v.w;
            zz[0] = a0[0] + pbv.x; zz[1] = a0[1] + pbv.y;
            zz[2] = a0[2] + pbv.z; zz[3] = a0[3] + pbv.w;
            int sb = (lh * 256 + wave * 64 + lg * 16) ^ ((lh & 7) << 4);
            *reinterpret_cast<f32x4*>(lds + XP + sb) = pz;
            *reinterpret_cast<f32x4*>(lds + XZ + sb) = zz;
        }
        {
            f32x4 pz, zz;
            pz[0] = c1[0] + b2v.x; pz[1] = c1[1] + b2v.y;
            pz[2] = c1[2] + b2v.z; pz[3] = c1[3] + b2v.w;
            zz[0] = a1[0] + pbv.x; zz[1] = a1[1] + pbv.y;
            zz[2] = a1[2] + pbv.z; zz[3] = a1[3] + pbv.w;
            int row = 16 + lh;
            int sb = (row * 256 + wave * 64 + lg * 16) ^ ((row & 7) << 4);
            *reinterpret_cast<f32x4*>(lds + XP + sb) = pz;
            *reinterpret_cast<f32x4*>(lds + XZ + sb) = zz;
        }
        LGKM_BAR();

        // WRITEBACK: thread streams rows rw and rw+16, 16B chunk cw
        #pragma unroll
        for (int ch = 0; ch < 2; ++ch) {
            int row = rw + ch * 16;
            int rb  = (row * 256 + cw * 4) ^ ((row & 7) << 4);
            float4 pr = *reinterpret_cast<const float4*>(lds + XP + rb);
            float4 zv = *reinterpret_cast<const float4*>(lds + XZ + rb);
            long ga = (row0 + row) * (long)DV + ph * 64 + cw;
            float4 va = (ch == 0) ? va0 : va1;
            float pa[4]  = {pr.x, pr.y, pr.z, pr.w};
            float za[4]  = {zv.x, zv.y, zv.z, zv.w};
            float vaa[4] = {va.x, va.y, va.z, va.w};
            float er[4], pc[4], f = 0.f;
            #pragma unroll
            for (int r = 0; r < 4; ++r) {
                float z = za[r];
                float prec = fmaxf(z, 0.f) + __logf(1.0f + __expf(-fabsf(z))) + 0.01f;
                float e = fminf(fmaxf(vaa[r] - pa[r], -3.f), 3.f);
                pc[r] = prec; er[r] = e;
                f += prec * e * e - __logf(prec);
            }
            float4 pc4 = {pc[0], pc[1], pc[2], pc[3]};
            float4 er4 = {er[0], er[1], er[2], er[3]};
            *reinterpret_cast<float4*>(outPred + ga) = pr;
            *reinterpret_cast<float4*>(outPrec + ga) = pc4;
            *reinterpret_cast<float4*>(outErr  + ga) = er4;
            if (ch == 0) facc0 += f; else facc1 += f;
        }
        LGKM_BAR();   // writeback reads done before next phase overwrites XP/XZ
    }

    // ---- F: thread owns fixed (row, 4-col chunk) across phases; reduce 16/row ----
    float* fpart = reinterpret_cast<float*>(lds + XP);   // [32 rows][16 chunks]
    fpart[rw * 16 + (tid & 15)]        = facc0;
    fpart[(rw + 16) * 16 + (tid & 15)] = facc1;
    __syncthreads();
    if (tid < 32) {
        const float* p = fpart + tid * 16;
        float s = 0.f;
        #pragma unroll
        for (int i = 0; i < 16; ++i) s += p[i];
        outF[row0 + tid] = s * (1.0f / 512.0f);
    }
}

extern "C" void kernel_launch(void* const* d_in, const int* in_sizes, int n_in,
                              void* d_out, int out_size, void* d_ws, size_t ws_size,
                              hipStream_t stream) {
    const float* key   = (const float*)d_in[0];
    const float* value = (const float*)d_in[1];
    const float* W1    = (const float*)d_in[2];
    const float* b1    = (const float*)d_in[3];
    const float* W2    = (const float*)d_in[4];
    const float* b2    = (const float*)d_in[5];
    const float* Wp    = (const float*)d_in[6];
    const float* pb    = (const float*)d_in[7];

    float* outF    = (float*)d_out;
    float* outPred = outF + BATCH;
    float* outPrec = outPred + (long)BATCH * DV;
    float* outErr  = outPrec + (long)BATCH * DV;

    conv_weights<<<160, 256, 0, stream>>>(W1, W2, Wp);
    fused_free_energy<<<BATCH / BMR, 256, 0, stream>>>(key, value, b1, b2, pb,
                                                       outF, outPred, outPrec, outErr);
}